// Round 11
// baseline (923.913 us; speedup 1.0000x reference)
//
#include <hip/hip_runtime.h>
#include <hip/hip_bf16.h>

// ---------------------------------------------------------------------------
// TemporalExtractor round 23 (base = r22):
//   attn_mfma: ones-row denominator eliminated. l[q] = sum_kk P[kk][q] is
//   computed in-register: each lane's 8 packed-bf16 P values cover kk-slots
//   {quad*4+0..3, 16+quad*4+0..3}; union over 4 quads = all 32 kk. Accumulate
//   the bf16-ROUNDED values (extracted from packed words -> identical to what
//   the ones-row MFMA summed) into latot[mt]; epilogue reduces over quads via
//   shfl_xor(16)+shfl_xor(32). Removes 2 MFMA + 1 Vt ds_read per iter (7.7%
//   of PV MFMAs), the ones-row init, Oa tile 13 (-8 VGPR), Vt rows 192..207
//   (LDS 62464 -> 60416 B). Everything else identical to r22 (LDS-roundtrip
//   P-transpose, Vt chunk-XOR swizzle, dual-buffer Ks, 8-phase gemm).
// ---------------------------------------------------------------------------

constexpr int Bb = 32, Tt = 1024, Ff = 64, Hh = 768, Gg = 4, Dd = 192;
constexpr float EPS = 1e-5f;
constexpr int WKMAX = 448;  // padded conv-weight K stride (7*64)

typedef __attribute__((ext_vector_type(8))) short short8;   // 8 bf16 = 4 VGPRs
typedef __attribute__((ext_vector_type(4))) float floatx4;  // MFMA acc

__device__ __forceinline__ void async_copy16(const void* g, void* l) {
  __builtin_amdgcn_global_load_lds(
      (const __attribute__((address_space(1))) unsigned int*)g,
      (__attribute__((address_space(3))) unsigned int*)l, 16, 0, 0);
}

__device__ __forceinline__ short bf16s(float f) {
  __hip_bfloat16 h = __float2bfloat16(f);
  return *(short*)&h;
}

__device__ __forceinline__ unsigned int pack_bf16(float lo, float hi) {
  return (unsigned int)(unsigned short)bf16s(lo) |
         ((unsigned int)(unsigned short)bf16s(hi) << 16);
}

__device__ __forceinline__ float2 block_reduce2(float a, float b, float* tmp) {
  int lane = threadIdx.x & 63, wid = threadIdx.x >> 6;
#pragma unroll
  for (int off = 32; off > 0; off >>= 1) {
    a += __shfl_down(a, off);
    b += __shfl_down(b, off);
  }
  if (lane == 0) { tmp[wid] = a; tmp[4 + wid] = b; }
  __syncthreads();
  if (threadIdx.x == 0) {
    tmp[0] = tmp[0] + tmp[1] + tmp[2] + tmp[3];
    tmp[4] = tmp[4] + tmp[5] + tmp[6] + tmp[7];
  }
  __syncthreads();
  float2 r; r.x = tmp[0]; r.y = tmp[4];
  return r;
}

// ---------------------------------------------------------------------------
// 0a) Attn/proj weight transpose+cast (Q pre-scaled by 192^-0.5)
// ---------------------------------------------------------------------------
__global__ __launch_bounds__(256) void wt_cast_kernel(
    const float* __restrict__ wq, const float* __restrict__ wk,
    const float* __restrict__ wv, const float* __restrict__ wp,
    __hip_bfloat16* __restrict__ wt) {
  const int z = blockIdx.z;
  const int m = z & 3, i = z >> 2;
  const float* src =
      (m == 0 ? wq : m == 1 ? wk : m == 2 ? wv : wp) + (size_t)i * Hh * Hh;
  const float sc = (m == 0) ? 0.0721687836f : 1.f;
  __shared__ float tile[32][33];
  const int n0 = blockIdx.x * 32, k0 = blockIdx.y * 32;
  const int tx = threadIdx.x & 31, ty = threadIdx.x >> 5;
#pragma unroll
  for (int r = 0; r < 4; r++)
    tile[ty + 8 * r][tx] = src[(size_t)(k0 + ty + 8 * r) * Hh + n0 + tx];
  __syncthreads();
#pragma unroll
  for (int r = 0; r < 4; r++)
    wt[((size_t)z * Hh + n0 + ty + 8 * r) * Hh + k0 + tx] =
        __float2bfloat16(tile[tx][ty + 8 * r] * sc);
}

// ---------------------------------------------------------------------------
// 0b) Conv weight cast
// ---------------------------------------------------------------------------
__global__ __launch_bounds__(256) void wcv_cast_kernel(
    const float* __restrict__ wf3, const float* __restrict__ wg3,
    const float* __restrict__ wf5, const float* __restrict__ wg5,
    const float* __restrict__ wf7, const float* __restrict__ wg7,
    __hip_bfloat16* __restrict__ wcv) {
  int idx = blockIdx.x * 256 + threadIdx.x;
  if (idx >= 3 * 512 * WKMAX) return;
  int j = idx / (512 * WKMAX);
  int rem = idx - j * 512 * WKMAX;
  int n = rem / WKMAX, k = rem % WKMAX;
  int Kw = 3 + 2 * j;
  float v = 0.f;
  if (k < Kw * 64) {
    const float* src = (n < 256) ? (j == 0 ? wf3 : j == 1 ? wf5 : wf7)
                                 : (j == 0 ? wg3 : j == 1 ? wg5 : wg7);
    v = src[(size_t)k * 256 + (n & 255)];
  }
  wcv[idx] = __float2bfloat16(v);
}

// 0c) x cast fp32 -> bf16
__global__ __launch_bounds__(256) void x_cast_kernel(
    const float* __restrict__ x, short* __restrict__ x16, int n8) {
  int idx = blockIdx.x * 256 + threadIdx.x;
  if (idx >= n8) return;
  const float4 a = ((const float4*)x)[idx * 2];
  const float4 b = ((const float4*)x)[idx * 2 + 1];
  short8 o;
  o[0] = bf16s(a.x); o[1] = bf16s(a.y); o[2] = bf16s(a.z); o[3] = bf16s(a.w);
  o[4] = bf16s(b.x); o[5] = bf16s(b.y); o[6] = bf16s(b.z); o[7] = bf16s(b.w);
  ((short8*)x16)[idx] = o;
}

// ---------------------------------------------------------------------------
// 1) Conv as implicit GEMM (unchanged)
// ---------------------------------------------------------------------------
__global__ __launch_bounds__(256) void conv_gemm_kernel(
    const short* __restrict__ x16, const short* __restrict__ wcv,
    short* __restrict__ yraw, int b0) {
  __shared__ __align__(16) short Asl[128 * 72];
  __shared__ __align__(16) short Bsl[128 * 72];
  const int t0 = blockIdx.x * 128, n0 = blockIdx.y * 128;
  const int bl = blockIdx.z / 3, j = blockIdx.z % 3;
  const int Kw = 3 + 2 * j, pad = j + 1;
  const int bglob = b0 + bl;
  const short* wb = wcv + (size_t)j * 512 * WKMAX;
  const int tid = threadIdx.x;
  const int lane = tid & 63;
  const int w = tid >> 6, wm = w >> 1, wn = w & 1;
  const int lm = lane & 15, quad = lane >> 4;

  floatx4 acc[4][4];
#pragma unroll
  for (int i = 0; i < 4; i++)
#pragma unroll
    for (int jj = 0; jj < 4; jj++) acc[i][jj] = (floatx4)0.f;

  for (int kk = 0; kk < Kw; kk++) {
    __syncthreads();
#pragma unroll
    for (int it = 0; it < 4; it++) {
      int s = it * 256 + tid;
      int row = s >> 3, c8 = s & 7;
      int t = t0 + row + kk - pad;
      short8 av = (short8)0;
      if (t >= 0 && t < Tt)
        av = *(const short8*)&x16[((size_t)bglob * Tt + t) * Ff + c8 * 8];
      *(short8*)&Asl[row * 72 + c8 * 8] = av;
      short8 bv = *(const short8*)&wb[(size_t)(n0 + row) * WKMAX + kk * 64 +
                                      c8 * 8];
      *(short8*)&Bsl[row * 72 + c8 * 8] = bv;
    }
    __syncthreads();
#pragma unroll
    for (int ks = 0; ks < 2; ks++) {
      short8 a[4], b[4];
#pragma unroll
      for (int i = 0; i < 4; i++)
        a[i] = *(const short8*)&Asl[(wm * 64 + i * 16 + lm) * 72 + ks * 32 +
                                    quad * 8];
#pragma unroll
      for (int jj = 0; jj < 4; jj++)
        b[jj] = *(const short8*)&Bsl[(wn * 64 + jj * 16 + lm) * 72 + ks * 32 +
                                     quad * 8];
#pragma unroll
      for (int i = 0; i < 4; i++)
#pragma unroll
        for (int jj = 0; jj < 4; jj++)
          acc[i][jj] = __builtin_amdgcn_mfma_f32_16x16x32_bf16(a[i], b[jj],
                                                               acc[i][jj],
                                                               0, 0, 0);
    }
  }

  const int rbase = quad * 4;
#pragma unroll
  for (int i = 0; i < 4; i++)
#pragma unroll
    for (int jj = 0; jj < 4; jj++) {
      int mrow = t0 + wm * 64 + i * 16 + rbase;
      int ncol = n0 + wn * 64 + jj * 16 + lm;
#pragma unroll
      for (int r = 0; r < 4; r++)
        yraw[((size_t)bl * Tt + mrow + r) * 1536 + j * 512 + ncol] =
            bf16s(acc[i][jj][r]);
    }
}

// ---------------------------------------------------------------------------
// 2) Fused gate + LayerNorm (unchanged)
// ---------------------------------------------------------------------------
__global__ __launch_bounds__(256) void gate_ln_kernel(
    const short* __restrict__ yraw, __hip_bfloat16* __restrict__ h16,
    const float* __restrict__ bf3, const float* __restrict__ bg3,
    const float* __restrict__ bf5, const float* __restrict__ bg5,
    const float* __restrict__ bf7, const float* __restrict__ bg7,
    const float* __restrict__ g, const float* __restrict__ bt) {
  __shared__ float red[8];
  const size_t row = blockIdx.x;
  float v[3], s = 0.f, ss = 0.f;
#pragma unroll
  for (int jj = 0; jj < 3; jj++) {
    int c = threadIdx.x + jj * 256;
    int br = c >> 8, cc = c & 255;
    const float* bfp = br == 0 ? bf3 : br == 1 ? bf5 : bf7;
    const float* bgp = br == 0 ? bg3 : br == 1 ? bg5 : bg7;
    __hip_bfloat16 rf = *(const __hip_bfloat16*)&yraw[row * 1536 + br * 512 + cc];
    __hip_bfloat16 rg =
        *(const __hip_bfloat16*)&yraw[row * 1536 + br * 512 + 256 + cc];
    float f = __bfloat162float(rf) + bfp[cc];
    float gt = __bfloat162float(rg) + bgp[cc];
    float a = f > 0.f ? f : 0.f;
    float t = a * (1.f / (1.f + __expf(-gt)));
    v[jj] = t; s += t; ss += t * t;
  }
  float2 r = block_reduce2(s, ss, red);
  float mu = r.x * (1.f / Hh);
  float var = r.y * (1.f / Hh) - mu * mu;
  float rs = rsqrtf(var + EPS);
#pragma unroll
  for (int jj = 0; jj < 3; jj++) {
    int c = threadIdx.x + jj * 256;
    float o = (v[jj] - mu) * rs * g[c] + bt[c];
    h16[row * Hh + c] = __float2bfloat16(o);
  }
}

// residual LN: h16 = LN(h16 + y16 + bp)   (bf16 in/out, fp32 math)
__global__ __launch_bounds__(256) void res_ln_kernel(
    __hip_bfloat16* __restrict__ h16, const __hip_bfloat16* __restrict__ y,
    const float* __restrict__ bp, const float* __restrict__ g,
    const float* __restrict__ bt) {
  __shared__ float red[8];
  const size_t row = blockIdx.x;
  float v[3], s = 0.f, ss = 0.f;
#pragma unroll
  for (int jj = 0; jj < 3; jj++) {
    int c = threadIdx.x + jj * 256;
    float t = __bfloat162float(h16[row * Hh + c]) +
              __bfloat162float(y[row * Hh + c]) + bp[c];
    v[jj] = t; s += t; ss += t * t;
  }
  float2 r = block_reduce2(s, ss, red);
  float mu = r.x * (1.f / Hh);
  float var = r.y * (1.f / Hh) - mu * mu;
  float rs = rsqrtf(var + EPS);
#pragma unroll
  for (int jj = 0; jj < 3; jj++) {
    int c = threadIdx.x + jj * 256;
    float o = (v[jj] - mu) * rs * g[c] + bt[c];
    h16[row * Hh + c] = __float2bfloat16(o);
  }
}

// ---------------------------------------------------------------------------
// 3) 256x256-tile GEMM, m201 8-phase schedule, BK=64, 2-buffer LDS.
//    (unchanged from round 16 -- see r16 header for the schedule ledger)
// ---------------------------------------------------------------------------
template <int MODE>
__global__ __launch_bounds__(512, 2) void gemm_8ph(
    const short* __restrict__ A, const short* __restrict__ Bt,
    short* __restrict__ out_q, short* __restrict__ out_k,
    short* __restrict__ out_v) {
  constexpr int K = 768;
  constexpr int NT = K / 64;                 // 12 K-tiles (BK=64)
  constexpr int NI = NT / 2;                 // 6 iters
  constexpr int NB = (MODE == 0) ? 9 : 3;    // 256-col blocks in N
  __shared__ __align__(16) short lds[65536]; // 2 x (A 16K + B 16K shorts)

  // bijective XCD-aware block swizzle (m204)
  const int nwg = gridDim.x;
  const int qq = nwg >> 3, rr = nwg & 7;
  const int xcd = blockIdx.x & 7, bidx = blockIdx.x >> 3;
  const int swz =
      (xcd < rr ? xcd * (qq + 1) : rr * (qq + 1) + (xcd - rr) * qq) + bidx;
  const int nb = swz % NB, mb = swz / NB;
  const int n0 = nb * 256, m0 = mb * 256;

  const int tid = threadIdx.x;
  const int lane = tid & 63, w = tid >> 6;
  const int lm = lane & 15, quad = lane >> 4;
  const int wm = w >> 2, wn = w & 3;

  // staging descriptors: linear LDS dest, inverse-swizzled global source.
  // half-tile = 128 rows x 64 k = 1024 16B-chunks = 512 thr x 2 loads.
  int srow[2], scol[2], dst8[2];
#pragma unroll
  for (int li = 0; li < 2; li++) {
    int c = li * 512 + tid;
    int ks = c >> 9, rem = c & 511;
    int reg = rem >> 6, cs = rem & 63;
    int cs2 = cs ^ (((cs >> 5) & 1) << 1);  // st_16x32 involution on chunks
    srow[li] = (reg << 4) + (cs2 >> 2);
    scol[li] = ks * 32 + (cs2 & 3) * 8;
    dst8[li] = ks * 8192 + rem * 8;
  }

#define STG(T, ISB, H)                                                     \
  {                                                                        \
    _Pragma("unroll") for (int li = 0; li < 2; li++) {                     \
      const short* sp = ((ISB) ? Bt : A) +                                 \
          (size_t)((((ISB) ? n0 : m0) + (H) * 128 + srow[li])) * K +       \
          (T) * 64 + scol[li];                                             \
      async_copy16(sp, &lds[((T) & 1) * 32768 + (ISB) * 16384 +            \
                            (H) * 4096 + dst8[li]]);                       \
    }                                                                      \
  }

  // swizzled ds_read offset within a 64B-row panel (short index)
  const int lane_sh = (lm * 32 + quad * 8) ^ ((lm >> 3) << 4);
  const int abase = wm * 8;  // A 16-row-region base
  const int bbase = wn * 4;  // B 16-row-region base

  floatx4 acc[8][4];
#pragma unroll
  for (int i = 0; i < 8; i++)
#pragma unroll
    for (int j = 0; j < 4; j++) acc[i][j] = (floatx4)0.f;

  short8 aF[4][2], bF[2][2];

#define LDA(CB, MH)                                                        \
  _Pragma("unroll") for (int mi = 0; mi < 4; mi++)                         \
    _Pragma("unroll") for (int ks = 0; ks < 2; ks++)                       \
      aF[mi][ks] = *(const short8*)&lds[(CB) + ks * 8192 +                 \
          (abase + (MH) * 4 + mi) * 512 + lane_sh];
#define LDB(CB, NH)                                                        \
  _Pragma("unroll") for (int nj = 0; nj < 2; nj++)                         \
    _Pragma("unroll") for (int ks = 0; ks < 2; ks++)                       \
      bF[nj][ks] = *(const short8*)&lds[(CB) + 16384 + ks * 8192 +         \
          (bbase + (NH) * 2 + nj) * 512 + lane_sh];
#define MM(MH, NH)                                                         \
  __builtin_amdgcn_s_setprio(1);                                           \
  _Pragma("unroll") for (int mi = 0; mi < 4; mi++)                         \
    _Pragma("unroll") for (int nj = 0; nj < 2; nj++)                       \
      _Pragma("unroll") for (int ks = 0; ks < 2; ks++)                     \
        acc[(MH) * 4 + mi][(NH) * 2 + nj] =                                \
            __builtin_amdgcn_mfma_f32_16x16x32_bf16(                       \
                aF[mi][ks], bF[nj][ks],                                    \
                acc[(MH) * 4 + mi][(NH) * 2 + nj], 0, 0, 0);               \
  __builtin_amdgcn_s_setprio(0);
#define BARRIER asm volatile("s_barrier" ::: "memory")
#define WAITV2 asm volatile("s_waitcnt vmcnt(2)" ::: "memory")
#define WAITV0 asm volatile("s_waitcnt vmcnt(0)" ::: "memory")

  // prologue: tile 0 fully staged + drained
  STG(0, 0, 0); STG(0, 0, 1); STG(0, 1, 0); STG(0, 1, 1);
  WAITV0;
  BARRIER;

#pragma unroll
  for (int i = 0; i < NI; i++) {
    const int T0 = 2 * i;
    // ---- ph1: (m0,n0) of tile T0 (buf0) ----
    LDA(0, 0); LDB(0, 0);
    STG(T0 + 1, 0, 1);
    if (i == 0) STG(1, 0, 0);  // A-top(1): ph8 slot of nonexistent iter -1
    BARRIER; MM(0, 0); BARRIER;
    // ---- ph2: (m0,n1) ----
    LDB(0, 1);
    STG(T0 + 1, 1, 0);
    BARRIER; MM(0, 1); BARRIER;
    // ---- ph3: (m1,n0) ----
    LDA(0, 1); LDB(0, 0);
    STG(T0 + 1, 1, 1);
    BARRIER; MM(1, 0); BARRIER;
    // ---- ph4: (m1,n1); tile T0+1 must be resident after this barrier ----
    LDB(0, 1);
    if (T0 + 2 < NT) STG(T0 + 2, 0, 0);
    BARRIER; MM(1, 1);
    if (i < NI - 1) { WAITV2; } else { WAITV0; }
    BARRIER;
    // ---- ph5: (m0,n0) of tile T0+1 (buf1) ----
    LDA(32768, 0); LDB(32768, 0);
    if (T0 + 2 < NT) STG(T0 + 2, 0, 1);
    BARRIER; MM(0, 0); BARRIER;
    // ---- ph6: (m0,n1) ----
    LDB(32768, 1);
    if (T0 + 2 < NT) STG(T0 + 2, 1, 0);
    BARRIER; MM(0, 1); BARRIER;
    // ---- ph7: (m1,n0) ----
    LDA(32768, 1); LDB(32768, 0);
    if (T0 + 2 < NT) STG(T0 + 2, 1, 1);
    BARRIER; MM(1, 0); BARRIER;
    // ---- ph8: (m1,n1); tile T0+2 must be resident after this barrier ----
    LDB(32768, 1);
    if (T0 + 3 < NT) STG(T0 + 3, 0, 0);
    BARRIER; MM(1, 1);
    if (i < NI - 1) {
      WAITV2;
      BARRIER;
    }
  }
#undef STG
#undef LDA
#undef LDB
#undef MM
#undef BARRIER
#undef WAITV2
#undef WAITV0

  const int rbase = quad * 4;
  if (MODE == 1) {
#pragma unroll
    for (int i = 0; i < 8; i++) {
      const int mrow = m0 + wm * 128 + i * 16 + rbase;
#pragma unroll
      for (int j = 0; j < 4; j++) {
        const int ncol = n0 + wn * 64 + j * 16 + lm;
#pragma unroll
        for (int r = 0; r < 4; r++)
          out_q[(size_t)(mrow + r) * Hh + ncol] = bf16s(acc[i][j][r]);
      }
    }
  } else {
    const int which = nb / 3;            // 0:q 1:k 2:v
    const int nbase = (nb % 3) * 256;
#pragma unroll
    for (int i = 0; i < 8; i++) {
      const int mrow = m0 + wm * 128 + i * 16 + rbase;
#pragma unroll
      for (int j = 0; j < 4; j++) {
        const int nl = nbase + wn * 64 + j * 16 + lm;
        if (which == 0) {
#pragma unroll
          for (int r = 0; r < 4; r++)
            out_q[(size_t)(mrow + r) * Hh + nl] = bf16s(acc[i][j][r]);
        } else if (which == 1) {
#pragma unroll
          for (int r = 0; r < 4; r++)
            out_k[(size_t)(mrow + r) * Hh + nl] = bf16s(acc[i][j][r]);
        } else {
          const int bL = mrow >> 10, ttok = mrow & 1023;
          const int g = nl / Dd, d = nl % Dd;
          short4 sv;
          sv.x = bf16s(acc[i][j][0]); sv.y = bf16s(acc[i][j][1]);
          sv.z = bf16s(acc[i][j][2]); sv.w = bf16s(acc[i][j][3]);
          *(short4*)&out_v[(((size_t)bL * Gg + g) * Dd + d) * Tt + ttok] = sv;
        }
      }
    }
  }
}

// ---------------------------------------------------------------------------
// 4) MFMA flash attention. r23: in-register denominator (no ones-row MFMA);
//    LDS-roundtrip P-transpose (r22); Vt chunk-XOR swizzle (r17).
// ---------------------------------------------------------------------------
__global__ __launch_bounds__(256, 2) void attn_mfma(
    const short* __restrict__ q16, const short* __restrict__ k16,
    const short* __restrict__ vt16, short* __restrict__ o16, int chunk4) {
  const int bg = blockIdx.x % chunk4;
  const int qb = blockIdx.x / chunk4;
  const int b = bg >> 2, g = bg & 3;
  const int q0 = qb * 128;
  const int tid = threadIdx.x;
  const int w = tid >> 6, lane = tid & 63, lm = lane & 15, quad = lane >> 4;

  __shared__ __align__(16) short Ks[2][32 * 200];   // [kk][d]
  __shared__ __align__(16) short Vt[2][192 * 32];   // [d][kk]
  __shared__ __align__(16) short Ps[8][640];        // [wave*2+mt][q=16][kk=32],
                                                    // row stride 40 shorts
  constexpr int VBUF = 192 * 32;

  short8 qf[2][6];
#pragma unroll
  for (int mt = 0; mt < 2; mt++)
#pragma unroll
    for (int ks = 0; ks < 6; ks++) {
      int tok = b * Tt + q0 + w * 32 + mt * 16 + lm;
      qf[mt][ks] = *(const short8*)&q16[(size_t)tok * Hh + g * Dd + ks * 32 +
                                        quad * 8];
    }

  floatx4 Oa[2][12];
#pragma unroll
  for (int mt = 0; mt < 2; mt++)
#pragma unroll
    for (int n = 0; n < 12; n++) Oa[mt][n] = (floatx4)0.f;
  float latot[2] = {0.f, 0.f};

  int krow[3], kcs[3];
  const short* kgp[3];
  const short* vgp[3];
  short* vld[3];
#pragma unroll
  for (int it = 0; it < 3; it++) {
    int s = it * 256 + tid;
    krow[it] = s / 24; kcs[it] = s - krow[it] * 24;
    kgp[it] = &k16[(size_t)(b * Tt + krow[it]) * Hh + g * Dd + kcs[it] * 8];
    // Vt chunk-XOR swizzle: LDS slot (d, c) holds global chunk c ^ ((d>>1)&3).
    vgp[it] = &vt16[(((size_t)b * Gg + g) * Dd + (s >> 2)) * Tt +
                    (size_t)(((s & 3) ^ ((s >> 3) & 3)) * 8)];
    vld[it] = (short*)&Vt[0][0] + (size_t)s * 8;
  }

  short8 kvK[3];
#pragma unroll
  for (int it = 0; it < 3; it++) kvK[it] = *(const short8*)kgp[it];
#pragma unroll
  for (int it = 0; it < 3; it++)
    *(short8*)&Ks[0][krow[it] * 200 + kcs[it] * 8] = kvK[it];
#pragma unroll
  for (int it = 0; it < 3; it++)
    kvK[it] = *(const short8*)(kgp[it] + (size_t)32 * Hh);
#pragma unroll
  for (int it = 0; it < 3; it++) async_copy16(vgp[it], vld[it]);

  for (int i = 0; i < 32; i++) {
    const int ib = i & 1;
    __syncthreads();

    if (i + 1 < 32) {
#pragma unroll
      for (int it = 0; it < 3; it++)
        *(short8*)&Ks[ib ^ 1][krow[it] * 200 + kcs[it] * 8] = kvK[it];
      const int vo = (i + 1) * 32;
#pragma unroll
      for (int it = 0; it < 3; it++)
        async_copy16(vgp[it] + vo, vld[it] + (ib ^ 1) * VBUF);
      if (i + 2 < 32) {
        const size_t ko = (size_t)(i + 2) * 32 * Hh;
#pragma unroll
        for (int it = 0; it < 3; it++)
          kvK[it] = *(const short8*)(kgp[it] + ko);
      }
    }

    floatx4 st[2][2];
#pragma unroll
    for (int mt = 0; mt < 2; mt++)
#pragma unroll
      for (int jj = 0; jj < 2; jj++) st[mt][jj] = (floatx4)0.f;
#pragma unroll
    for (int ks = 0; ks < 6; ks++) {
      short8 k0 = *(const short8*)&Ks[ib][lm * 200 + ks * 32 + quad * 8];
      short8 k1 = *(const short8*)&Ks[ib][(16 + lm) * 200 + ks * 32 + quad * 8];
      st[0][0] = __builtin_amdgcn_mfma_f32_16x16x32_bf16(k0, qf[0][ks], st[0][0], 0, 0, 0);
      st[0][1] = __builtin_amdgcn_mfma_f32_16x16x32_bf16(k1, qf[0][ks], st[0][1], 0, 0, 0);
      st[1][0] = __builtin_amdgcn_mfma_f32_16x16x32_bf16(k0, qf[1][ks], st[1][0], 0, 0, 0);
      st[1][1] = __builtin_amdgcn_mfma_f32_16x16x32_bf16(k1, qf[1][ks], st[1][1], 0, 0, 0);
    }

    // fixed-reference softmax: P = exp(S); P-transpose via wave-private LDS
    // round-trip (r22). Denominator: accumulate the bf16-rounded P values
    // (extracted from the packed words -> identical numerics to the old
    // ones-row MFMA sum) into latot; quad-reduce in the epilogue.
#pragma unroll
    for (int mt = 0; mt < 2; mt++) {
      float p[2][4];
#pragma unroll
      for (int jj = 0; jj < 2; jj++)
#pragma unroll
        for (int r = 0; r < 4; r++) p[jj][r] = __expf(st[mt][jj][r]);

      int2 w0, w1;
      w0.x = (int)pack_bf16(p[0][0], p[0][1]);
      w0.y = (int)pack_bf16(p[0][2], p[0][3]);
      w1.x = (int)pack_bf16(p[1][0], p[1][1]);
      w1.y = (int)pack_bf16(p[1][2], p[1][3]);
      latot[mt] += __int_as_float(w0.x << 16) +
                   __int_as_float(w0.x & 0xffff0000) +
                   __int_as_float(w0.y << 16) +
                   __int_as_float(w0.y & 0xffff0000) +
                   __int_as_float(w1.x << 16) +
                   __int_as_float(w1.x & 0xffff0000) +
                   __int_as_float(w1.y << 16) +
                   __int_as_float(w1.y & 0xffff0000);
      short* pb = &Ps[w * 2 + mt][0];
      *(int2*)&pb[lm * 40 + quad * 4] = w0;       // jj=0: kk = quad*4 + 0..3
      *(int2*)&pb[lm * 40 + 16 + quad * 4] = w1;  // jj=1: kk = 16+quad*4+0..3
    }
    short8 ptf[2];
#pragma unroll
    for (int mt = 0; mt < 2; mt++)
      ptf[mt] = *(const short8*)&Ps[w * 2 + mt][lm * 40 + quad * 8];

#pragma unroll
    for (int n = 0; n < 12; n++) {
      // swizzled Vt read: slot = quad ^ ((lm>>1)&3) within the row
      short8 vf = *(const short8*)&Vt[ib][(n * 16 + lm) * 32 +
                                          ((quad ^ ((lm >> 1) & 3)) * 8)];
      Oa[0][n] = __builtin_amdgcn_mfma_f32_16x16x32_bf16(vf, ptf[0], Oa[0][n], 0, 0, 0);
      Oa[1][n] = __builtin_amdgcn_mfma_f32_16x16x32_bf16(vf, ptf[1], Oa[1][n], 0, 0, 0);
    }
  }

  // epilogue: l via quad-reduction (lanes lm, lm+16, lm+32, lm+48)
#pragma unroll
  for (int mt = 0; mt < 2; mt++) {
    float l = latot[mt];
    l += __shfl_xor(l, 16);
    l += __shfl_xor(l, 32);
    float inv = 1.f / l;
    int tok = b * Tt + q0 + w * 32 + mt * 16 + lm;
#pragma unroll
    for (int n = 0; n < 12; n++) {
      short4 sv;
      sv.x = bf16s(Oa[mt][n][0] * inv);
      sv.y = bf16s(Oa[mt][n][1] * inv);
      sv.z = bf16s(Oa[mt][n][2] * inv);
      sv.w = bf16s(Oa[mt][n][3] * inv);
      *(short4*)&o16[(size_t)tok * Hh + g * Dd + n * 16 + quad * 4] = sv;
    }
  }
}

// ---------------------------------------------------------------------------
// 5) Pool, two-stage (unchanged)
// ---------------------------------------------------------------------------
__global__ __launch_bounds__(256) void pool_stage1(
    const __hip_bfloat16* __restrict__ h16, float* __restrict__ ppart,
    int b0) {
  int idx = blockIdx.x * 256 + threadIdx.x;
  int seg = blockIdx.y;
  int bl = idx / Hh, c = idx % Hh;
  float s = 0.f, ss = 0.f;
  const __hip_bfloat16* hp = &h16[((size_t)bl * Tt + seg * 128) * Hh + c];
  for (int t = 0; t < 128; t++) {
    float v = __bfloat162float(hp[(size_t)t * Hh]);
    s += v; ss += v * v;
  }
  float* o = &ppart[(((size_t)(b0 + bl) * 8 + seg) * 2) * Hh + c];
  o[0] = s;
  o[Hh] = ss;
}

__global__ __launch_bounds__(256) void pool_stage2(
    const float* __restrict__ ppart, float* __restrict__ pool) {
  int idx = blockIdx.x * 256 + threadIdx.x;
  int b = idx / Hh, c = idx % Hh;
  float s = 0.f, ss = 0.f;
#pragma unroll
  for (int seg = 0; seg < 8; seg++) {
    const float* o = &ppart[(((size_t)b * 8 + seg) * 2) * Hh + c];
    s += o[0]; ss += o[Hh];
  }
  float mu = s * (1.f / Tt);
  float var = ss * (1.f / Tt) - mu * mu;
  pool[(size_t)b * 1536 + c] = mu;
  pool[(size_t)b * 1536 + 768 + c] = sqrtf(fmaxf(var, 0.f));
}

// ---------------------------------------------------------------------------
// 6) Final projection, split-K two-stage (unchanged)
// ---------------------------------------------------------------------------
__global__ __launch_bounds__(256) void final_partial(
    const float* __restrict__ pool, const float* __restrict__ pw,
    float* __restrict__ part) {
  const int n = blockIdx.x * 256 + threadIdx.x;
  const int bg = blockIdx.y * 4;
  const int ks = blockIdx.z, k0 = ks * 192;
  __shared__ float ms[4][192];
  for (int e = threadIdx.x; e < 4 * 192; e += 256) {
    int bb = e / 192, kk = e % 192;
    ms[bb][kk] = pool[(size_t)(bg + bb) * 1536 + k0 + kk];
  }
  __syncthreads();
  float a0 = 0.f, a1 = 0.f, a2 = 0.f, a3 = 0.f;
  for (int kk = 0; kk < 192; kk++) {
    float wv = pw[(size_t)(k0 + kk) * Hh + n];
    a0 = fmaf(ms[0][kk], wv, a0);
    a1 = fmaf(ms[1][kk], wv, a1);
    a2 = fmaf(ms[2][kk], wv, a2);
    a3 = fmaf(ms[3][kk], wv, a3);
  }
  part[((size_t)ks * Bb + bg + 0) * Hh + n] = a0;
  part[((size_t)ks * Bb + bg + 1) * Hh + n] = a1;
  part[((size_t)ks * Bb + bg + 2) * Hh + n] = a2;
  part[((size_t)ks * Bb + bg + 3) * Hh + n] = a3;
}

__global__ __launch_bounds__(256) void final_stage2(
    const float* __restrict__ part, const float* __restrict__ pb,
    const float* __restrict__ g, const float* __restrict__ bt,
    float* __restrict__ out) {
  __shared__ float red[8];
  const int b = blockIdx.x;
  float v[3], s = 0.f, ss = 0.f;
#pragma unroll
  for (int jj = 0; jj < 3; jj++) {
    int n = threadIdx.x + jj * 256;
    float a = pb[n];
#pragma unroll
    for (int ks = 0; ks < 8; ks++) a += part[((size_t)ks * Bb + b) * Hh + n];
    v[jj] = a; s += a; ss += a * a;
  }
  float2 r = block_reduce2(s, ss, red);
  float mu = r.x * (1.f / Hh);
  float var = r.y * (1.f / Hh) - mu * mu;
  float rs = rsqrtf(var + EPS);
#pragma unroll
  for (int jj = 0; jj < 3; jj++) {
    int n = threadIdx.x + jj * 256;
    float o = (v[jj] - mu) * rs * g[n] + bt[n];
    out[(size_t)b * Hh + n] = o > 0.f ? o : 0.f;
  }
}

// ---------------------------------------------------------------------------
extern "C" void kernel_launch(void* const* d_in, const int* in_sizes, int n_in,
                              void* d_out, int out_size, void* d_ws,
                              size_t ws_size, hipStream_t stream) {
  (void)in_sizes; (void)n_in; (void)out_size;
  const float* x = (const float*)d_in[0];
  const float* cw[3][4];
  for (int j = 0; j < 3; j++)
    for (int p2 = 0; p2 < 4; p2++) cw[j][p2] = (const float*)d_in[1 + j * 4 + p2];
  const float* conv_ln_g = (const float*)d_in[13];
  const float* conv_ln_b = (const float*)d_in[14];
  const float* wq = (const float*)d_in[15];
  const float* wk = (const float*)d_in[16];
  const float* wv = (const float*)d_in[17];
  const float* wp = (const float*)d_in[18];
  const float* bp = (const float*)d_in[19];
  const float* lng = (const float*)d_in[20];
  const float* lnb = (const float*)d_in[21];
  const float* proj_w = (const float*)d_in[22];
  const float* proj_b = (const float*)d_in[23];
  const float* proj_ln_g = (const float*)d_in[24];
  const float* proj_ln_b = (const float*)d_in[25];
  float* out = (float*)d_out;

  // --- workspace: 8 B per token-channel element -----------------------------
  const size_t perb = (size_t)Tt * Hh;
  const size_t fixedB = 8ull * Hh * Hh * 2 + 3ull * 512 * WKMAX * 2 +
                        (size_t)Bb * Tt * Ff * 2 + (size_t)Bb * 2 * Hh * 4 +
                        (size_t)Bb * 8 * 2 * Hh * 4 + 8ull * Bb * Hh * 4;
  int chunk = Bb;
  while (chunk > 1 && 8ull * perb * chunk + fixedB > ws_size) chunk >>= 1;

  const size_t crow = perb * (size_t)chunk;
  char* p = (char*)d_ws;
  __hip_bfloat16* h16 = (__hip_bfloat16*)p;  p += crow * 2;
  short* q16 = (short*)p;            p += crow * 2;
  short* k16 = (short*)p;            p += crow * 2;   // contiguous after q16
  short* v16t = (short*)p;           p += crow * 2;
  short* yraw16 = q16;               // conv raw spans q16||k16 (4 B/elem)
  short* y16 = k16;                  // proj output reuses k16
  __hip_bfloat16* wt = (__hip_bfloat16*)p;   p += 8ull * Hh * Hh * 2;
  __hip_bfloat16* wcv = (__hip_bfloat16*)p;  p += 3ull * 512 * WKMAX * 2;
  short* x16 = (short*)p;            p += (size_t)Bb * Tt * Ff * 2;
  float* pool = (float*)p;           p += (size_t)Bb * 2 * Hh * 4;
  float* ppart = (float*)p;          p += (size_t)Bb * 8 * 2 * Hh * 4;
  float* fpart = (float*)p;

  // one-time casts
  wt_cast_kernel<<<dim3(24, 24, 8), 256, 0, stream>>>(wq, wk, wv, wp, wt);
  wcv_cast_kernel<<<(3 * 512 * WKMAX + 255) / 256, 256, 0, stream>>>(
      cw[0][0], cw[0][2], cw[1][0], cw[1][2], cw[2][0], cw[2][2], wcv);
  x_cast_kernel<<<(Bb * Tt * Ff / 8 + 255) / 256, 256, 0, stream>>>(
      x, x16, Bb * Tt * Ff / 8);

  const short* wts = (const short*)wt;

  for (int b0 = 0; b0 < Bb; b0 += chunk) {
    const int M = chunk * Tt;

    conv_gemm_kernel<<<dim3(Tt / 128, 4, chunk * 3), 256, 0, stream>>>(
        x16, (const short*)wcv, yraw16, b0);
    gate_ln_kernel<<<M, 256, 0, stream>>>(
        yraw16, h16, cw[0][1], cw[0][3], cw[1][1], cw[1][3], cw[2][1],
        cw[2][3], conv_ln_g, conv_ln_b);

    for (int i = 0; i < 2; i++) {
      const short* wqkv = wts + (size_t)(i * 4) * Hh * Hh;
      const short* wtp = wts + (size_t)(i * 4 + 3) * Hh * Hh;
      gemm_8ph<0><<<dim3(9 * (M / 256)), 512, 0, stream>>>(
          (const short*)h16, wqkv, q16, k16, v16t);
      attn_mfma<<<dim3(chunk * Gg * (Tt / 128)), 256, 0, stream>>>(
          q16, k16, v16t, q16, chunk * Gg);
      gemm_8ph<1><<<dim3(3 * (M / 256)), 512, 0, stream>>>(
          q16, wtp, y16, nullptr, nullptr);
      res_ln_kernel<<<M, 256, 0, stream>>>(h16, (const __hip_bfloat16*)y16,
                                           bp + (size_t)i * Hh,
                                           lng + (size_t)i * Hh,
                                           lnb + (size_t)i * Hh);
    }

    pool_stage1<<<dim3((chunk * Hh) / 256, 8), 256, 0, stream>>>(h16, ppart,
                                                                 b0);
  }

  pool_stage2<<<(Bb * Hh) / 256, 256, 0, stream>>>(ppart, pool);
  final_partial<<<dim3(3, 8, 8), 256, 0, stream>>>(pool, proj_w, fpart);
  final_stage2<<<Bb, 256, 0, stream>>>(fpart, proj_b, proj_ln_g, proj_ln_b,
                                       out);
}

// Round 12
// 867.648 us; speedup vs baseline: 1.0648x; 1.0648x over previous
//
#include <hip/hip_runtime.h>
#include <hip/hip_bf16.h>

// ---------------------------------------------------------------------------
// TemporalExtractor round 24 (base = r23):
//   gemm_8ph re-tiled to BM=BN=128 (BK=64, 4 waves, 64 KB LDS) so TWO blocks
//   co-reside per CU. Derivation: at 128-KB LDS the CU holds 1 block, so all
//   96 barriers/block stall every resident wave together -- MFMA pipe ~34%
//   busy with zero cross-block overlap (m114 mechanism unavailable). The
//   8-phase schedule, STG slots, counted-vmcnt ledger (2 loads/STG/thread,
//   vmcnt(2) at ph4/ph8), st_16x32 involution and XCD swizzle port 1:1 to
//   the half tile (64-row staging halves, 8 read regions). Cost: A-panel
//   fetched 18x vs 9x (+~50MB, still far from BW-bound).
//   attn (r23: in-register denominator, LDS-roundtrip P-transpose, Vt
//   chunk-XOR swizzle) and all other kernels unchanged.
// ---------------------------------------------------------------------------

constexpr int Bb = 32, Tt = 1024, Ff = 64, Hh = 768, Gg = 4, Dd = 192;
constexpr float EPS = 1e-5f;
constexpr int WKMAX = 448;  // padded conv-weight K stride (7*64)

typedef __attribute__((ext_vector_type(8))) short short8;   // 8 bf16 = 4 VGPRs
typedef __attribute__((ext_vector_type(4))) float floatx4;  // MFMA acc

__device__ __forceinline__ void async_copy16(const void* g, void* l) {
  __builtin_amdgcn_global_load_lds(
      (const __attribute__((address_space(1))) unsigned int*)g,
      (__attribute__((address_space(3))) unsigned int*)l, 16, 0, 0);
}

__device__ __forceinline__ short bf16s(float f) {
  __hip_bfloat16 h = __float2bfloat16(f);
  return *(short*)&h;
}

__device__ __forceinline__ unsigned int pack_bf16(float lo, float hi) {
  return (unsigned int)(unsigned short)bf16s(lo) |
         ((unsigned int)(unsigned short)bf16s(hi) << 16);
}

__device__ __forceinline__ float2 block_reduce2(float a, float b, float* tmp) {
  int lane = threadIdx.x & 63, wid = threadIdx.x >> 6;
#pragma unroll
  for (int off = 32; off > 0; off >>= 1) {
    a += __shfl_down(a, off);
    b += __shfl_down(b, off);
  }
  if (lane == 0) { tmp[wid] = a; tmp[4 + wid] = b; }
  __syncthreads();
  if (threadIdx.x == 0) {
    tmp[0] = tmp[0] + tmp[1] + tmp[2] + tmp[3];
    tmp[4] = tmp[4] + tmp[5] + tmp[6] + tmp[7];
  }
  __syncthreads();
  float2 r; r.x = tmp[0]; r.y = tmp[4];
  return r;
}

// ---------------------------------------------------------------------------
// 0a) Attn/proj weight transpose+cast (Q pre-scaled by 192^-0.5)
// ---------------------------------------------------------------------------
__global__ __launch_bounds__(256) void wt_cast_kernel(
    const float* __restrict__ wq, const float* __restrict__ wk,
    const float* __restrict__ wv, const float* __restrict__ wp,
    __hip_bfloat16* __restrict__ wt) {
  const int z = blockIdx.z;
  const int m = z & 3, i = z >> 2;
  const float* src =
      (m == 0 ? wq : m == 1 ? wk : m == 2 ? wv : wp) + (size_t)i * Hh * Hh;
  const float sc = (m == 0) ? 0.0721687836f : 1.f;
  __shared__ float tile[32][33];
  const int n0 = blockIdx.x * 32, k0 = blockIdx.y * 32;
  const int tx = threadIdx.x & 31, ty = threadIdx.x >> 5;
#pragma unroll
  for (int r = 0; r < 4; r++)
    tile[ty + 8 * r][tx] = src[(size_t)(k0 + ty + 8 * r) * Hh + n0 + tx];
  __syncthreads();
#pragma unroll
  for (int r = 0; r < 4; r++)
    wt[((size_t)z * Hh + n0 + ty + 8 * r) * Hh + k0 + tx] =
        __float2bfloat16(tile[tx][ty + 8 * r] * sc);
}

// ---------------------------------------------------------------------------
// 0b) Conv weight cast
// ---------------------------------------------------------------------------
__global__ __launch_bounds__(256) void wcv_cast_kernel(
    const float* __restrict__ wf3, const float* __restrict__ wg3,
    const float* __restrict__ wf5, const float* __restrict__ wg5,
    const float* __restrict__ wf7, const float* __restrict__ wg7,
    __hip_bfloat16* __restrict__ wcv) {
  int idx = blockIdx.x * 256 + threadIdx.x;
  if (idx >= 3 * 512 * WKMAX) return;
  int j = idx / (512 * WKMAX);
  int rem = idx - j * 512 * WKMAX;
  int n = rem / WKMAX, k = rem % WKMAX;
  int Kw = 3 + 2 * j;
  float v = 0.f;
  if (k < Kw * 64) {
    const float* src = (n < 256) ? (j == 0 ? wf3 : j == 1 ? wf5 : wf7)
                                 : (j == 0 ? wg3 : j == 1 ? wg5 : wg7);
    v = src[(size_t)k * 256 + (n & 255)];
  }
  wcv[idx] = __float2bfloat16(v);
}

// 0c) x cast fp32 -> bf16
__global__ __launch_bounds__(256) void x_cast_kernel(
    const float* __restrict__ x, short* __restrict__ x16, int n8) {
  int idx = blockIdx.x * 256 + threadIdx.x;
  if (idx >= n8) return;
  const float4 a = ((const float4*)x)[idx * 2];
  const float4 b = ((const float4*)x)[idx * 2 + 1];
  short8 o;
  o[0] = bf16s(a.x); o[1] = bf16s(a.y); o[2] = bf16s(a.z); o[3] = bf16s(a.w);
  o[4] = bf16s(b.x); o[5] = bf16s(b.y); o[6] = bf16s(b.z); o[7] = bf16s(b.w);
  ((short8*)x16)[idx] = o;
}

// ---------------------------------------------------------------------------
// 1) Conv as implicit GEMM (unchanged)
// ---------------------------------------------------------------------------
__global__ __launch_bounds__(256) void conv_gemm_kernel(
    const short* __restrict__ x16, const short* __restrict__ wcv,
    short* __restrict__ yraw, int b0) {
  __shared__ __align__(16) short Asl[128 * 72];
  __shared__ __align__(16) short Bsl[128 * 72];
  const int t0 = blockIdx.x * 128, n0 = blockIdx.y * 128;
  const int bl = blockIdx.z / 3, j = blockIdx.z % 3;
  const int Kw = 3 + 2 * j, pad = j + 1;
  const int bglob = b0 + bl;
  const short* wb = wcv + (size_t)j * 512 * WKMAX;
  const int tid = threadIdx.x;
  const int lane = tid & 63;
  const int w = tid >> 6, wm = w >> 1, wn = w & 1;
  const int lm = lane & 15, quad = lane >> 4;

  floatx4 acc[4][4];
#pragma unroll
  for (int i = 0; i < 4; i++)
#pragma unroll
    for (int jj = 0; jj < 4; jj++) acc[i][jj] = (floatx4)0.f;

  for (int kk = 0; kk < Kw; kk++) {
    __syncthreads();
#pragma unroll
    for (int it = 0; it < 4; it++) {
      int s = it * 256 + tid;
      int row = s >> 3, c8 = s & 7;
      int t = t0 + row + kk - pad;
      short8 av = (short8)0;
      if (t >= 0 && t < Tt)
        av = *(const short8*)&x16[((size_t)bglob * Tt + t) * Ff + c8 * 8];
      *(short8*)&Asl[row * 72 + c8 * 8] = av;
      short8 bv = *(const short8*)&wb[(size_t)(n0 + row) * WKMAX + kk * 64 +
                                      c8 * 8];
      *(short8*)&Bsl[row * 72 + c8 * 8] = bv;
    }
    __syncthreads();
#pragma unroll
    for (int ks = 0; ks < 2; ks++) {
      short8 a[4], b[4];
#pragma unroll
      for (int i = 0; i < 4; i++)
        a[i] = *(const short8*)&Asl[(wm * 64 + i * 16 + lm) * 72 + ks * 32 +
                                    quad * 8];
#pragma unroll
      for (int jj = 0; jj < 4; jj++)
        b[jj] = *(const short8*)&Bsl[(wn * 64 + jj * 16 + lm) * 72 + ks * 32 +
                                     quad * 8];
#pragma unroll
      for (int i = 0; i < 4; i++)
#pragma unroll
        for (int jj = 0; jj < 4; jj++)
          acc[i][jj] = __builtin_amdgcn_mfma_f32_16x16x32_bf16(a[i], b[jj],
                                                               acc[i][jj],
                                                               0, 0, 0);
    }
  }

  const int rbase = quad * 4;
#pragma unroll
  for (int i = 0; i < 4; i++)
#pragma unroll
    for (int jj = 0; jj < 4; jj++) {
      int mrow = t0 + wm * 64 + i * 16 + rbase;
      int ncol = n0 + wn * 64 + jj * 16 + lm;
#pragma unroll
      for (int r = 0; r < 4; r++)
        yraw[((size_t)bl * Tt + mrow + r) * 1536 + j * 512 + ncol] =
            bf16s(acc[i][jj][r]);
    }
}

// ---------------------------------------------------------------------------
// 2) Fused gate + LayerNorm (unchanged)
// ---------------------------------------------------------------------------
__global__ __launch_bounds__(256) void gate_ln_kernel(
    const short* __restrict__ yraw, __hip_bfloat16* __restrict__ h16,
    const float* __restrict__ bf3, const float* __restrict__ bg3,
    const float* __restrict__ bf5, const float* __restrict__ bg5,
    const float* __restrict__ bf7, const float* __restrict__ bg7,
    const float* __restrict__ g, const float* __restrict__ bt) {
  __shared__ float red[8];
  const size_t row = blockIdx.x;
  float v[3], s = 0.f, ss = 0.f;
#pragma unroll
  for (int jj = 0; jj < 3; jj++) {
    int c = threadIdx.x + jj * 256;
    int br = c >> 8, cc = c & 255;
    const float* bfp = br == 0 ? bf3 : br == 1 ? bf5 : bf7;
    const float* bgp = br == 0 ? bg3 : br == 1 ? bg5 : bg7;
    __hip_bfloat16 rf = *(const __hip_bfloat16*)&yraw[row * 1536 + br * 512 + cc];
    __hip_bfloat16 rg =
        *(const __hip_bfloat16*)&yraw[row * 1536 + br * 512 + 256 + cc];
    float f = __bfloat162float(rf) + bfp[cc];
    float gt = __bfloat162float(rg) + bgp[cc];
    float a = f > 0.f ? f : 0.f;
    float t = a * (1.f / (1.f + __expf(-gt)));
    v[jj] = t; s += t; ss += t * t;
  }
  float2 r = block_reduce2(s, ss, red);
  float mu = r.x * (1.f / Hh);
  float var = r.y * (1.f / Hh) - mu * mu;
  float rs = rsqrtf(var + EPS);
#pragma unroll
  for (int jj = 0; jj < 3; jj++) {
    int c = threadIdx.x + jj * 256;
    float o = (v[jj] - mu) * rs * g[c] + bt[c];
    h16[row * Hh + c] = __float2bfloat16(o);
  }
}

// residual LN: h16 = LN(h16 + y16 + bp)   (bf16 in/out, fp32 math)
__global__ __launch_bounds__(256) void res_ln_kernel(
    __hip_bfloat16* __restrict__ h16, const __hip_bfloat16* __restrict__ y,
    const float* __restrict__ bp, const float* __restrict__ g,
    const float* __restrict__ bt) {
  __shared__ float red[8];
  const size_t row = blockIdx.x;
  float v[3], s = 0.f, ss = 0.f;
#pragma unroll
  for (int jj = 0; jj < 3; jj++) {
    int c = threadIdx.x + jj * 256;
    float t = __bfloat162float(h16[row * Hh + c]) +
              __bfloat162float(y[row * Hh + c]) + bp[c];
    v[jj] = t; s += t; ss += t * t;
  }
  float2 r = block_reduce2(s, ss, red);
  float mu = r.x * (1.f / Hh);
  float var = r.y * (1.f / Hh) - mu * mu;
  float rs = rsqrtf(var + EPS);
#pragma unroll
  for (int jj = 0; jj < 3; jj++) {
    int c = threadIdx.x + jj * 256;
    float o = (v[jj] - mu) * rs * g[c] + bt[c];
    h16[row * Hh + c] = __float2bfloat16(o);
  }
}

// ---------------------------------------------------------------------------
// 3) 128x128-tile GEMM, m201 8-phase schedule, BK=64, 2-buffer LDS (64 KB
//    -> 2 blocks/CU). 4 waves (2M x 2N), per-wave out 64x64. Same STG slot
//    assignment and counted-vmcnt ledger as the 256-tile version (2 loads
//    per STG per thread; vmcnt(2) at ph4/ph8, tail 2->0). Staging halves
//    are 64 rows x 64 k = 512 chunks = 256 thr x 2 loads; st_16x32
//    involution identical per 16-row region.
//    MODE 0: A[M][768] x Bt[2304][768]^T -> Q | K | V(transposed store)
//    MODE 1: A[M][768] x Bt[768][768]^T  -> C[M][768]
// ---------------------------------------------------------------------------
template <int MODE>
__global__ __launch_bounds__(256, 2) void gemm_8ph(
    const short* __restrict__ A, const short* __restrict__ Bt,
    short* __restrict__ out_q, short* __restrict__ out_k,
    short* __restrict__ out_v) {
  constexpr int K = 768;
  constexpr int NT = K / 64;                 // 12 K-tiles (BK=64)
  constexpr int NI = NT / 2;                 // 6 iters
  constexpr int NB = (MODE == 0) ? 18 : 6;   // 128-col blocks in N
  __shared__ __align__(16) short lds[32768]; // 2 x (A 8K + B 8K shorts)

  // bijective XCD-aware block swizzle (m204)
  const int nwg = gridDim.x;
  const int qq = nwg >> 3, rr = nwg & 7;
  const int xcd = blockIdx.x & 7, bidx = blockIdx.x >> 3;
  const int swz =
      (xcd < rr ? xcd * (qq + 1) : rr * (qq + 1) + (xcd - rr) * qq) + bidx;
  const int nb = swz % NB, mb = swz / NB;
  const int n0 = nb * 128, m0 = mb * 128;

  const int tid = threadIdx.x;
  const int lane = tid & 63, w = tid >> 6;   // 4 waves
  const int lm = lane & 15, quad = lane >> 4;
  const int wm = w >> 1, wn = w & 1;

  // staging: half-tile = 64 rows x 64 k = 512 16B-chunks = 256 thr x 2 loads.
  // Linear LDS dest, inverse-swizzled global source (st_16x32 involution per
  // 16-row region of 64 chunks).
  int srow[2], scol[2], dst8[2];
#pragma unroll
  for (int li = 0; li < 2; li++) {
    int c = li * 256 + tid;
    int ks = c >> 8, rem = c & 255;
    int reg = rem >> 6, cs = rem & 63;
    int cs2 = cs ^ (((cs >> 5) & 1) << 1);
    srow[li] = (reg << 4) + (cs2 >> 2);      // 0..63 within the half
    scol[li] = ks * 32 + (cs2 & 3) * 8;
    dst8[li] = ks * 4096 + rem * 8;          // + H*2048 added in STG
  }

#define STG(T, ISB, H)                                                     \
  {                                                                        \
    _Pragma("unroll") for (int li = 0; li < 2; li++) {                     \
      const short* sp = ((ISB) ? Bt : A) +                                 \
          (size_t)((((ISB) ? n0 : m0) + (H) * 64 + srow[li])) * K +        \
          (T) * 64 + scol[li];                                             \
      async_copy16(sp, &lds[((T) & 1) * 16384 + (ISB) * 8192 +             \
                            (H) * 2048 + dst8[li]]);                       \
    }                                                                      \
  }

  // swizzled ds_read offset within a 64B-row panel (short index)
  const int lane_sh = (lm * 32 + quad * 8) ^ ((lm >> 3) << 4);
  const int abase = wm * 4;  // A 16-row-region base (8 regions / 128 rows)
  const int bbase = wn * 4;  // B 16-row-region base

  floatx4 acc[4][4];
#pragma unroll
  for (int i = 0; i < 4; i++)
#pragma unroll
    for (int j = 0; j < 4; j++) acc[i][j] = (floatx4)0.f;

  short8 aF[2][2], bF[2][2];

#define LDA(CB, MH)                                                        \
  _Pragma("unroll") for (int mi = 0; mi < 2; mi++)                         \
    _Pragma("unroll") for (int ks = 0; ks < 2; ks++)                       \
      aF[mi][ks] = *(const short8*)&lds[(CB) + ks * 4096 +                 \
          (abase + (MH) * 2 + mi) * 512 + lane_sh];
#define LDB(CB, NH)                                                        \
  _Pragma("unroll") for (int nj = 0; nj < 2; nj++)                         \
    _Pragma("unroll") for (int ks = 0; ks < 2; ks++)                       \
      bF[nj][ks] = *(const short8*)&lds[(CB) + 8192 + ks * 4096 +          \
          (bbase + (NH) * 2 + nj) * 512 + lane_sh];
#define MM(MH, NH)                                                         \
  __builtin_amdgcn_s_setprio(1);                                           \
  _Pragma("unroll") for (int mi = 0; mi < 2; mi++)                         \
    _Pragma("unroll") for (int nj = 0; nj < 2; nj++)                       \
      _Pragma("unroll") for (int ks = 0; ks < 2; ks++)                     \
        acc[(MH) * 2 + mi][(NH) * 2 + nj] =                                \
            __builtin_amdgcn_mfma_f32_16x16x32_bf16(                       \
                aF[mi][ks], bF[nj][ks],                                    \
                acc[(MH) * 2 + mi][(NH) * 2 + nj], 0, 0, 0);               \
  __builtin_amdgcn_s_setprio(0);
#define BARRIER asm volatile("s_barrier" ::: "memory")
#define WAITV2 asm volatile("s_waitcnt vmcnt(2)" ::: "memory")
#define WAITV0 asm volatile("s_waitcnt vmcnt(0)" ::: "memory")

  // prologue: tile 0 fully staged + drained
  STG(0, 0, 0); STG(0, 0, 1); STG(0, 1, 0); STG(0, 1, 1);
  WAITV0;
  BARRIER;

#pragma unroll
  for (int i = 0; i < NI; i++) {
    const int T0 = 2 * i;
    // ---- ph1: (m0,n0) of tile T0 (buf0) ----
    LDA(0, 0); LDB(0, 0);
    STG(T0 + 1, 0, 1);
    if (i == 0) STG(1, 0, 0);  // A-top(1): ph8 slot of nonexistent iter -1
    BARRIER; MM(0, 0); BARRIER;
    // ---- ph2: (m0,n1) ----
    LDB(0, 1);
    STG(T0 + 1, 1, 0);
    BARRIER; MM(0, 1); BARRIER;
    // ---- ph3: (m1,n0) ----
    LDA(0, 1); LDB(0, 0);
    STG(T0 + 1, 1, 1);
    BARRIER; MM(1, 0); BARRIER;
    // ---- ph4: (m1,n1); tile T0+1 must be resident after this barrier ----
    LDB(0, 1);
    if (T0 + 2 < NT) STG(T0 + 2, 0, 0);
    BARRIER; MM(1, 1);
    if (i < NI - 1) { WAITV2; } else { WAITV0; }
    BARRIER;
    // ---- ph5: (m0,n0) of tile T0+1 (buf1) ----
    LDA(16384, 0); LDB(16384, 0);
    if (T0 + 2 < NT) STG(T0 + 2, 0, 1);
    BARRIER; MM(0, 0); BARRIER;
    // ---- ph6: (m0,n1) ----
    LDB(16384, 1);
    if (T0 + 2 < NT) STG(T0 + 2, 1, 0);
    BARRIER; MM(0, 1); BARRIER;
    // ---- ph7: (m1,n0) ----
    LDA(16384, 1); LDB(16384, 0);
    if (T0 + 2 < NT) STG(T0 + 2, 1, 1);
    BARRIER; MM(1, 0); BARRIER;
    // ---- ph8: (m1,n1); tile T0+2 must be resident after this barrier ----
    LDB(16384, 1);
    if (T0 + 3 < NT) STG(T0 + 3, 0, 0);
    BARRIER; MM(1, 1);
    if (i < NI - 1) {
      WAITV2;
      BARRIER;
    }
  }
#undef STG
#undef LDA
#undef LDB
#undef MM
#undef BARRIER
#undef WAITV2
#undef WAITV0

  const int rbase = quad * 4;
  if (MODE == 1) {
#pragma unroll
    for (int i = 0; i < 4; i++) {
      const int mrow = m0 + wm * 64 + i * 16 + rbase;
#pragma unroll
      for (int j = 0; j < 4; j++) {
        const int ncol = n0 + wn * 64 + j * 16 + lm;
#pragma unroll
        for (int r = 0; r < 4; r++)
          out_q[(size_t)(mrow + r) * Hh + ncol] = bf16s(acc[i][j][r]);
      }
    }
  } else {
    const int which = nb / 6;            // 0:q 1:k 2:v
    const int nbase = (nb % 6) * 128;
#pragma unroll
    for (int i = 0; i < 4; i++) {
      const int mrow = m0 + wm * 64 + i * 16 + rbase;
#pragma unroll
      for (int j = 0; j < 4; j++) {
        const int nl = nbase + wn * 64 + j * 16 + lm;
        if (which == 0) {
#pragma unroll
          for (int r = 0; r < 4; r++)
            out_q[(size_t)(mrow + r) * Hh + nl] = bf16s(acc[i][j][r]);
        } else if (which == 1) {
#pragma unroll
          for (int r = 0; r < 4; r++)
            out_k[(size_t)(mrow + r) * Hh + nl] = bf16s(acc[i][j][r]);
        } else {
          const int bL = mrow >> 10, ttok = mrow & 1023;
          const int g = nl / Dd, d = nl % Dd;
          short4 sv;
          sv.x = bf16s(acc[i][j][0]); sv.y = bf16s(acc[i][j][1]);
          sv.z = bf16s(acc[i][j][2]); sv.w = bf16s(acc[i][j][3]);
          *(short4*)&out_v[(((size_t)bL * Gg + g) * Dd + d) * Tt + ttok] = sv;
        }
      }
    }
  }
}

// ---------------------------------------------------------------------------
// 4) MFMA flash attention (unchanged from round 23: in-register denominator,
//    LDS-roundtrip P-transpose, Vt chunk-XOR swizzle, dual-buffer Ks)
// ---------------------------------------------------------------------------
__global__ __launch_bounds__(256, 2) void attn_mfma(
    const short* __restrict__ q16, const short* __restrict__ k16,
    const short* __restrict__ vt16, short* __restrict__ o16, int chunk4) {
  const int bg = blockIdx.x % chunk4;
  const int qb = blockIdx.x / chunk4;
  const int b = bg >> 2, g = bg & 3;
  const int q0 = qb * 128;
  const int tid = threadIdx.x;
  const int w = tid >> 6, lane = tid & 63, lm = lane & 15, quad = lane >> 4;

  __shared__ __align__(16) short Ks[2][32 * 200];   // [kk][d]
  __shared__ __align__(16) short Vt[2][192 * 32];   // [d][kk]
  __shared__ __align__(16) short Ps[8][640];        // [wave*2+mt][q=16][kk=32],
                                                    // row stride 40 shorts
  constexpr int VBUF = 192 * 32;

  short8 qf[2][6];
#pragma unroll
  for (int mt = 0; mt < 2; mt++)
#pragma unroll
    for (int ks = 0; ks < 6; ks++) {
      int tok = b * Tt + q0 + w * 32 + mt * 16 + lm;
      qf[mt][ks] = *(const short8*)&q16[(size_t)tok * Hh + g * Dd + ks * 32 +
                                        quad * 8];
    }

  floatx4 Oa[2][12];
#pragma unroll
  for (int mt = 0; mt < 2; mt++)
#pragma unroll
    for (int n = 0; n < 12; n++) Oa[mt][n] = (floatx4)0.f;
  float latot[2] = {0.f, 0.f};

  int krow[3], kcs[3];
  const short* kgp[3];
  const short* vgp[3];
  short* vld[3];
#pragma unroll
  for (int it = 0; it < 3; it++) {
    int s = it * 256 + tid;
    krow[it] = s / 24; kcs[it] = s - krow[it] * 24;
    kgp[it] = &k16[(size_t)(b * Tt + krow[it]) * Hh + g * Dd + kcs[it] * 8];
    // Vt chunk-XOR swizzle: LDS slot (d, c) holds global chunk c ^ ((d>>1)&3).
    vgp[it] = &vt16[(((size_t)b * Gg + g) * Dd + (s >> 2)) * Tt +
                    (size_t)(((s & 3) ^ ((s >> 3) & 3)) * 8)];
    vld[it] = (short*)&Vt[0][0] + (size_t)s * 8;
  }

  short8 kvK[3];
#pragma unroll
  for (int it = 0; it < 3; it++) kvK[it] = *(const short8*)kgp[it];
#pragma unroll
  for (int it = 0; it < 3; it++)
    *(short8*)&Ks[0][krow[it] * 200 + kcs[it] * 8] = kvK[it];
#pragma unroll
  for (int it = 0; it < 3; it++)
    kvK[it] = *(const short8*)(kgp[it] + (size_t)32 * Hh);
#pragma unroll
  for (int it = 0; it < 3; it++) async_copy16(vgp[it], vld[it]);

  for (int i = 0; i < 32; i++) {
    const int ib = i & 1;
    __syncthreads();

    if (i + 1 < 32) {
#pragma unroll
      for (int it = 0; it < 3; it++)
        *(short8*)&Ks[ib ^ 1][krow[it] * 200 + kcs[it] * 8] = kvK[it];
      const int vo = (i + 1) * 32;
#pragma unroll
      for (int it = 0; it < 3; it++)
        async_copy16(vgp[it] + vo, vld[it] + (ib ^ 1) * VBUF);
      if (i + 2 < 32) {
        const size_t ko = (size_t)(i + 2) * 32 * Hh;
#pragma unroll
        for (int it = 0; it < 3; it++)
          kvK[it] = *(const short8*)(kgp[it] + ko);
      }
    }

    floatx4 st[2][2];
#pragma unroll
    for (int mt = 0; mt < 2; mt++)
#pragma unroll
      for (int jj = 0; jj < 2; jj++) st[mt][jj] = (floatx4)0.f;
#pragma unroll
    for (int ks = 0; ks < 6; ks++) {
      short8 k0 = *(const short8*)&Ks[ib][lm * 200 + ks * 32 + quad * 8];
      short8 k1 = *(const short8*)&Ks[ib][(16 + lm) * 200 + ks * 32 + quad * 8];
      st[0][0] = __builtin_amdgcn_mfma_f32_16x16x32_bf16(k0, qf[0][ks], st[0][0], 0, 0, 0);
      st[0][1] = __builtin_amdgcn_mfma_f32_16x16x32_bf16(k1, qf[0][ks], st[0][1], 0, 0, 0);
      st[1][0] = __builtin_amdgcn_mfma_f32_16x16x32_bf16(k0, qf[1][ks], st[1][0], 0, 0, 0);
      st[1][1] = __builtin_amdgcn_mfma_f32_16x16x32_bf16(k1, qf[1][ks], st[1][1], 0, 0, 0);
    }

    // fixed-reference softmax: P = exp(S); LDS-roundtrip P-transpose (r22);
    // denominator from bf16-rounded packed values (r23).
#pragma unroll
    for (int mt = 0; mt < 2; mt++) {
      float p[2][4];
#pragma unroll
      for (int jj = 0; jj < 2; jj++)
#pragma unroll
        for (int r = 0; r < 4; r++) p[jj][r] = __expf(st[mt][jj][r]);

      int2 w0, w1;
      w0.x = (int)pack_bf16(p[0][0], p[0][1]);
      w0.y = (int)pack_bf16(p[0][2], p[0][3]);
      w1.x = (int)pack_bf16(p[1][0], p[1][1]);
      w1.y = (int)pack_bf16(p[1][2], p[1][3]);
      latot[mt] += __int_as_float(w0.x << 16) +
                   __int_as_float(w0.x & 0xffff0000) +
                   __int_as_float(w0.y << 16) +
                   __int_as_float(w0.y & 0xffff0000) +
                   __int_as_float(w1.x << 16) +
                   __int_as_float(w1.x & 0xffff0000) +
                   __int_as_float(w1.y << 16) +
                   __int_as_float(w1.y & 0xffff0000);
      short* pb = &Ps[w * 2 + mt][0];
      *(int2*)&pb[lm * 40 + quad * 4] = w0;       // jj=0: kk = quad*4 + 0..3
      *(int2*)&pb[lm * 40 + 16 + quad * 4] = w1;  // jj=1: kk = 16+quad*4+0..3
    }
    short8 ptf[2];
#pragma unroll
    for (int mt = 0; mt < 2; mt++)
      ptf[mt] = *(const short8*)&Ps[w * 2 + mt][lm * 40 + quad * 8];

#pragma unroll
    for (int n = 0; n < 12; n++) {
      // swizzled Vt read: slot = quad ^ ((lm>>1)&3) within the row
      short8 vf = *(const short8*)&Vt[ib][(n * 16 + lm) * 32 +
                                          ((quad ^ ((lm >> 1) & 3)) * 8)];
      Oa[0][n] = __builtin_amdgcn_mfma_f32_16x16x32_bf16(vf, ptf[0], Oa[0][n], 0, 0, 0);
      Oa[1][n] = __builtin_amdgcn_mfma_f32_16x16x32_bf16(vf, ptf[1], Oa[1][n], 0, 0, 0);
    }
  }

  // epilogue: l via quad-reduction (lanes lm, lm+16, lm+32, lm+48)
#pragma unroll
  for (int mt = 0; mt < 2; mt++) {
    float l = latot[mt];
    l += __shfl_xor(l, 16);
    l += __shfl_xor(l, 32);
    float inv = 1.f / l;
    int tok = b * Tt + q0 + w * 32 + mt * 16 + lm;
#pragma unroll
    for (int n = 0; n < 12; n++) {
      short4 sv;
      sv.x = bf16s(Oa[mt][n][0] * inv);
      sv.y = bf16s(Oa[mt][n][1] * inv);
      sv.z = bf16s(Oa[mt][n][2] * inv);
      sv.w = bf16s(Oa[mt][n][3] * inv);
      *(short4*)&o16[(size_t)tok * Hh + g * Dd + n * 16 + quad * 4] = sv;
    }
  }
}

// ---------------------------------------------------------------------------
// 5) Pool, two-stage (unchanged)
// ---------------------------------------------------------------------------
__global__ __launch_bounds__(256) void pool_stage1(
    const __hip_bfloat16* __restrict__ h16, float* __restrict__ ppart,
    int b0) {
  int idx = blockIdx.x * 256 + threadIdx.x;
  int seg = blockIdx.y;
  int bl = idx / Hh, c = idx % Hh;
  float s = 0.f, ss = 0.f;
  const __hip_bfloat16* hp = &h16[((size_t)bl * Tt + seg * 128) * Hh + c];
  for (int t = 0; t < 128; t++) {
    float v = __bfloat162float(hp[(size_t)t * Hh]);
    s += v; ss += v * v;
  }
  float* o = &ppart[(((size_t)(b0 + bl) * 8 + seg) * 2) * Hh + c];
  o[0] = s;
  o[Hh] = ss;
}

__global__ __launch_bounds__(256) void pool_stage2(
    const float* __restrict__ ppart, float* __restrict__ pool) {
  int idx = blockIdx.x * 256 + threadIdx.x;
  int b = idx / Hh, c = idx % Hh;
  float s = 0.f, ss = 0.f;
#pragma unroll
  for (int seg = 0; seg < 8; seg++) {
    const float* o = &ppart[(((size_t)b * 8 + seg) * 2) * Hh + c];
    s += o[0]; ss += o[Hh];
  }
  float mu = s * (1.f / Tt);
  float var = ss * (1.f / Tt) - mu * mu;
  pool[(size_t)b * 1536 + c] = mu;
  pool[(size_t)b * 1536 + 768 + c] = sqrtf(fmaxf(var, 0.f));
}

// ---------------------------------------------------------------------------
// 6) Final projection, split-K two-stage (unchanged)
// ---------------------------------------------------------------------------
__global__ __launch_bounds__(256) void final_partial(
    const float* __restrict__ pool, const float* __restrict__ pw,
    float* __restrict__ part) {
  const int n = blockIdx.x * 256 + threadIdx.x;
  const int bg = blockIdx.y * 4;
  const int ks = blockIdx.z, k0 = ks * 192;
  __shared__ float ms[4][192];
  for (int e = threadIdx.x; e < 4 * 192; e += 256) {
    int bb = e / 192, kk = e % 192;
    ms[bb][kk] = pool[(size_t)(bg + bb) * 1536 + k0 + kk];
  }
  __syncthreads();
  float a0 = 0.f, a1 = 0.f, a2 = 0.f, a3 = 0.f;
  for (int kk = 0; kk < 192; kk++) {
    float wv = pw[(size_t)(k0 + kk) * Hh + n];
    a0 = fmaf(ms[0][kk], wv, a0);
    a1 = fmaf(ms[1][kk], wv, a1);
    a2 = fmaf(ms[2][kk], wv, a2);
    a3 = fmaf(ms[3][kk], wv, a3);
  }
  part[((size_t)ks * Bb + bg + 0) * Hh + n] = a0;
  part[((size_t)ks * Bb + bg + 1) * Hh + n] = a1;
  part[((size_t)ks * Bb + bg + 2) * Hh + n] = a2;
  part[((size_t)ks * Bb + bg + 3) * Hh + n] = a3;
}

__global__ __launch_bounds__(256) void final_stage2(
    const float* __restrict__ part, const float* __restrict__ pb,
    const float* __restrict__ g, const float* __restrict__ bt,
    float* __restrict__ out) {
  __shared__ float red[8];
  const int b = blockIdx.x;
  float v[3], s = 0.f, ss = 0.f;
#pragma unroll
  for (int jj = 0; jj < 3; jj++) {
    int n = threadIdx.x + jj * 256;
    float a = pb[n];
#pragma unroll
    for (int ks = 0; ks < 8; ks++) a += part[((size_t)ks * Bb + b) * Hh + n];
    v[jj] = a; s += a; ss += a * a;
  }
  float2 r = block_reduce2(s, ss, red);
  float mu = r.x * (1.f / Hh);
  float var = r.y * (1.f / Hh) - mu * mu;
  float rs = rsqrtf(var + EPS);
#pragma unroll
  for (int jj = 0; jj < 3; jj++) {
    int n = threadIdx.x + jj * 256;
    float o = (v[jj] - mu) * rs * g[n] + bt[n];
    out[(size_t)b * Hh + n] = o > 0.f ? o : 0.f;
  }
}

// ---------------------------------------------------------------------------
extern "C" void kernel_launch(void* const* d_in, const int* in_sizes, int n_in,
                              void* d_out, int out_size, void* d_ws,
                              size_t ws_size, hipStream_t stream) {
  (void)in_sizes; (void)n_in; (void)out_size;
  const float* x = (const float*)d_in[0];
  const float* cw[3][4];
  for (int j = 0; j < 3; j++)
    for (int p2 = 0; p2 < 4; p2++) cw[j][p2] = (const float*)d_in[1 + j * 4 + p2];
  const float* conv_ln_g = (const float*)d_in[13];
  const float* conv_ln_b = (const float*)d_in[14];
  const float* wq = (const float*)d_in[15];
  const float* wk = (const float*)d_in[16];
  const float* wv = (const float*)d_in[17];
  const float* wp = (const float*)d_in[18];
  const float* bp = (const float*)d_in[19];
  const float* lng = (const float*)d_in[20];
  const float* lnb = (const float*)d_in[21];
  const float* proj_w = (const float*)d_in[22];
  const float* proj_b = (const float*)d_in[23];
  const float* proj_ln_g = (const float*)d_in[24];
  const float* proj_ln_b = (const float*)d_in[25];
  float* out = (float*)d_out;

  // --- workspace: 8 B per token-channel element -----------------------------
  const size_t perb = (size_t)Tt * Hh;
  const size_t fixedB = 8ull * Hh * Hh * 2 + 3ull * 512 * WKMAX * 2 +
                        (size_t)Bb * Tt * Ff * 2 + (size_t)Bb * 2 * Hh * 4 +
                        (size_t)Bb * 8 * 2 * Hh * 4 + 8ull * Bb * Hh * 4;
  int chunk = Bb;
  while (chunk > 1 && 8ull * perb * chunk + fixedB > ws_size) chunk >>= 1;

  const size_t crow = perb * (size_t)chunk;
  char* p = (char*)d_ws;
  __hip_bfloat16* h16 = (__hip_bfloat16*)p;  p += crow * 2;
  short* q16 = (short*)p;            p += crow * 2;
  short* k16 = (short*)p;            p += crow * 2;   // contiguous after q16
  short* v16t = (short*)p;           p += crow * 2;
  short* yraw16 = q16;               // conv raw spans q16||k16 (4 B/elem)
  short* y16 = k16;                  // proj output reuses k16
  __hip_bfloat16* wt = (__hip_bfloat16*)p;   p += 8ull * Hh * Hh * 2;
  __hip_bfloat16* wcv = (__hip_bfloat16*)p;  p += 3ull * 512 * WKMAX * 2;
  short* x16 = (short*)p;            p += (size_t)Bb * Tt * Ff * 2;
  float* pool = (float*)p;           p += (size_t)Bb * 2 * Hh * 4;
  float* ppart = (float*)p;          p += (size_t)Bb * 8 * 2 * Hh * 4;
  float* fpart = (float*)p;

  // one-time casts
  wt_cast_kernel<<<dim3(24, 24, 8), 256, 0, stream>>>(wq, wk, wv, wp, wt);
  wcv_cast_kernel<<<(3 * 512 * WKMAX + 255) / 256, 256, 0, stream>>>(
      cw[0][0], cw[0][2], cw[1][0], cw[1][2], cw[2][0], cw[2][2], wcv);
  x_cast_kernel<<<(Bb * Tt * Ff / 8 + 255) / 256, 256, 0, stream>>>(
      x, x16, Bb * Tt * Ff / 8);

  const short* wts = (const short*)wt;

  for (int b0 = 0; b0 < Bb; b0 += chunk) {
    const int M = chunk * Tt;

    conv_gemm_kernel<<<dim3(Tt / 128, 4, chunk * 3), 256, 0, stream>>>(
        x16, (const short*)wcv, yraw16, b0);
    gate_ln_kernel<<<M, 256, 0, stream>>>(
        yraw16, h16, cw[0][1], cw[0][3], cw[1][1], cw[1][3], cw[2][1],
        cw[2][3], conv_ln_g, conv_ln_b);

    for (int i = 0; i < 2; i++) {
      const short* wqkv = wts + (size_t)(i * 4) * Hh * Hh;
      const short* wtp = wts + (size_t)(i * 4 + 3) * Hh * Hh;
      gemm_8ph<0><<<dim3(18 * (M / 128)), 256, 0, stream>>>(
          (const short*)h16, wqkv, q16, k16, v16t);
      attn_mfma<<<dim3(chunk * Gg * (Tt / 128)), 256, 0, stream>>>(
          q16, k16, v16t, q16, chunk * Gg);
      gemm_8ph<1><<<dim3(6 * (M / 128)), 256, 0, stream>>>(
          q16, wtp, y16, nullptr, nullptr);
      res_ln_kernel<<<M, 256, 0, stream>>>(h16, (const __hip_bfloat16*)y16,
                                           bp + (size_t)i * Hh,
                                           lng + (size_t)i * Hh,
                                           lnb + (size_t)i * Hh);
    }

    pool_stage1<<<dim3((chunk * Hh) / 256, 8), 256, 0, stream>>>(h16, ppart,
                                                                 b0);
  }

  pool_stage2<<<(Bb * Hh) / 256, 256, 0, stream>>>(ppart, pool);
  final_partial<<<dim3(3, 8, 8), 256, 0, stream>>>(pool, proj_w, fpart);
  final_stage2<<<Bb, 256, 0, stream>>>(fpart, proj_b, proj_ln_g, proj_ln_b,
                                       out);
}